// Round 1
// 319.186 us; speedup vs baseline: 1.1648x; 1.1648x over previous
//
#include <hip/hip_runtime.h>
#include <hip/hip_bf16.h>

typedef __hip_bfloat16 bf16;
typedef unsigned short ushort_t;
typedef __attribute__((ext_vector_type(8))) short short8;
typedef __attribute__((ext_vector_type(4))) short short4_t;
typedef __attribute__((ext_vector_type(4))) float f32x4;
typedef __attribute__((ext_vector_type(2))) float f32x2;

#define B_ 16
#define N_ 2000
#define E_ 3000
#define C_ 17
#define W_ 12
#define D_ 16
#define O_ 256
#define NB_ 3
#define KPAD 2048  // padded K/m stride (and padded S row stride)
#define KI_ 51     // 3*17 diffusion taps
#define SEGS 15    // k_hodge e1 segments
#define ECH 200    // e1 chunk per segment (SEGS*ECH = E_)

static __device__ __forceinline__ ushort_t f2b(float f) {
  bf16 h = __float2bfloat16(f);
  return *reinterpret_cast<ushort_t*>(&h);
}
static __device__ __forceinline__ float b2f_u(ushort_t u) {
  bf16 h = *reinterpret_cast<bf16*>(&u);
  return __bfloat162float(h);
}
__device__ __forceinline__ int idxval(const int* p, int i) {
  int iv = p[i];
  if (iv >= 0 && iv < 1000000) return iv;
  return (int)__int_as_float(iv);
}

// ---------------------------------------------------------------------------
// S = softmax(relu(ne@ne^T), diag=stay) rows -> bf16, row stride KPAD=2048,
// cols [2000,2048) zero, rows [2000,2048) zero (grid 2048). ne staged via LDS.
// ---------------------------------------------------------------------------
__global__ void k_S(const float* __restrict__ ne, const int* __restrict__ stay,
                    ushort_t* __restrict__ S) {
  const int i = blockIdx.x;
  const int t = threadIdx.x;
  if (i >= N_) {  // uniform per-block branch, no syncthreads on this path
#pragma unroll
    for (int it = 0; it < 8; ++it) S[(long)i*KPAD + t + it*256] = 0;
    return;
  }
  __shared__ float ne_l[512*20];
  __shared__ float reds[4];
  f32x4 nei[4];
#pragma unroll
  for (int q = 0; q < 4; ++q) nei[q] = *(const f32x4*)(ne + i*16 + q*4);
  const float stayf = (float)(*stay);
  float vals[8];
  float s = 0.f;
  for (int c = 0; c < 4; ++c) {
    __syncthreads();
#pragma unroll
    for (int u = 0; u < 8; ++u) {
      int unit = t + u*256;
      int row = unit >> 2, dq = unit & 3;
      int gj = c*512 + row;
      f32x4 v = {0.f,0.f,0.f,0.f};
      if (gj < N_) v = *(const f32x4*)(ne + gj*16 + dq*4);
      *(f32x4*)(ne_l + row*20 + dq*4) = v;
    }
    __syncthreads();
#pragma unroll
    for (int r = 0; r < 2; ++r) {
      int row_l = t + r*256;
      int j = c*512 + row_l;
      float e = 0.f;
      if (j < N_) {
        f32x4 a4 = {0.f,0.f,0.f,0.f};
#pragma unroll
        for (int q = 0; q < 4; ++q) a4 += nei[q] * (*(const f32x4*)(ne_l + row_l*20 + q*4));
        float dot = a4.x + a4.y + a4.z + a4.w;
        float v = dot > 0.f ? dot : 0.f;
        if (j == i) v = stayf;
        e = __expf(v);
        s += e;
      }
      vals[2*c + r] = e;
    }
  }
#pragma unroll
  for (int off = 32; off > 0; off >>= 1) s += __shfl_xor(s, off, 64);
  if ((t & 63) == 0) reds[t >> 6] = s;
  __syncthreads();
  s = reds[0] + reds[1] + reds[2] + reds[3];
  const float inv = 1.f/s;
#pragma unroll
  for (int it = 0; it < 8; ++it) {
    int j = t + it*256;
    S[(long)i*KPAD + j] = f2b(vals[it]*inv);  // vals==0 for j>=N_ -> stores 0
  }
}

// ---------------------------------------------------------------------------
// Fused independent small kernels (block-range dispatch):
//  [0,188) u/v; [188,313) xw; [313,2313) g rowsums; [2313,2601) BT1 build
// ---------------------------------------------------------------------------
__global__ void k_small(const float* __restrict__ xew, const int* __restrict__ bidx,
                        const float* __restrict__ lw, const float* __restrict__ lb,
                        const int* __restrict__ jc, float* __restrict__ u,
                        float* __restrict__ v,
                        const float* __restrict__ xwin, const float* __restrict__ Tp,
                        float* __restrict__ xw,
                        const float* __restrict__ gw, float* __restrict__ g,
                        const float* __restrict__ x, ushort_t* __restrict__ BT1) {
  const int bid = blockIdx.x;
  const int t = threadIdx.x;
  if (bid < 188) {
    int idx = bid*256 + t;
    if (idx >= B_*E_) return;
    int b = idx / E_, e = idx - b*E_;
    const float lwf = lw[0], lbf = lb[0];
    float uu = 0.f, vv = 0.f;
#pragma unroll
    for (int f = 0; f < NB_; ++f) {
      int tt = idxval(bidx, f);
      if (tt < 0) tt = 0;
      if (tt >= W_) tt = W_ - 1;
      float val = xew[(b*W_ + tt)*E_ + e]*lwf + lbf;
      uu += val;
      vv += (float)(NB_ - 1 - f)*val;
    }
    u[idx] = uu;
    v[idx] = vv*(float)(*jc);
  } else if (bid < 313) {
    int idx = (bid - 188)*256 + t;
    int b = idx / N_, n = idx - b*N_;
    float s = 0.f;
#pragma unroll
    for (int tt = 0; tt < W_; ++tt) s += xwin[(b*W_ + tt)*N_ + n]*Tp[tt];
    xw[idx] = s;
  } else if (bid < 2313) {
    int i = bid - 313;
    float s = 0.f;
    for (int j = t; j < N_; j += 256) s += gw[(long)i*N_ + j];
#pragma unroll
    for (int off = 32; off > 0; off >>= 1) s += __shfl_xor(s, off, 64);
    __shared__ float red[4];
    if ((t & 63) == 0) red[t >> 6] = s;
    __syncthreads();
    if (t == 0) g[i] = red[0] + red[1] + red[2] + red[3];
  } else {
    int j = bid - 2313;
    int bb = j / C_, cc = j - bb*C_;
#pragma unroll
    for (int uu = 0; uu < 8; ++uu) {
      int n = t + uu*256;
      float vv = 0.f;
      if (bb < B_ && n < N_) vv = x[(bb*N_ + n)*C_ + cc];
      BT1[(long)j*KPAD + n] = f2b(vv);
    }
  }
}

// ---------------------------------------------------------------------------
// MFMA GEMM v2: C[j][m] = sum_k A[m][k]*B[j][k], K=2048 (zero-padded), no
// split-K, no atomics. Grid (128 m-tiles of 16, 2 j-halves of 144); 256 thr.
// Triple-buffered global_load_lds (16B) staging; counted vmcnt + raw
// s_barrier so prefetch loads stay in flight across barriers. LDS linear
// with XOR involution swizzle x^=((x>>7)&7)<<4 applied to BOTH the global
// source address and the ds_read address (bank-conflict-free b128 reads).
// Epilogue: f32x4 store to Cf; optionally bf16 store to Cb (pad m>=2000 = 0).
// ---------------------------------------------------------------------------
__global__ __launch_bounds__(256) void k_mm2(const ushort_t* __restrict__ A,
                                             const ushort_t* __restrict__ BT,
                                             float* __restrict__ Cf,
                                             ushort_t* __restrict__ Cb,
                                             int writeCb) {
  __shared__ ushort_t lds[3][10240];  // 3 x 20480 B: [0,2048)=A 16x128B, [2048,20480)=B 144x128B
  const int t = threadIdx.x;
  const int m0 = blockIdx.x * 16;
  const int j0 = blockIdx.y * 144;
  const int wv = t >> 6, lane = t & 63;
  const int lm = lane & 15, lg = lane >> 4;
  const char* gA = (const char*)A + (size_t)m0 * (KPAD*2);
  const char* gB = (const char*)BT + (size_t)j0 * (KPAD*2);

  f32x4 acc[3];
#pragma unroll
  for (int q = 0; q < 3; ++q) acc[q] = (f32x4){0.f,0.f,0.f,0.f};

  auto stage = [&](int p, int s) {
    const long kb = (long)s * 128;  // 64 bf16 per K-step
#pragma unroll
    for (int u = 0; u < 5; ++u) {
      int x = (u*256 + t) << 4;                 // linear LDS byte this lane fills
      int y = x ^ (((x >> 7) & 7) << 4);        // involution: fetch swizzled source
      int r = y >> 7, c = y & 127;              // region row (A:0..15, B:16..159), col bytes
      const char* gp = (r < 16) ? gA + (long)r*(KPAD*2) + kb + c
                                : gB + (long)(r-16)*(KPAD*2) + kb + c;
      __builtin_amdgcn_global_load_lds(
          (const __attribute__((address_space(1))) void*)gp,
          (__attribute__((address_space(3))) void*)(&lds[p][u*2048 + wv*512]),
          16, 0, 0);
    }
  };

  auto compute = [&](int p) {
    const char* base = (const char*)&lds[p][0];
#pragma unroll
    for (int kg = 0; kg < 2; ++kg) {
      int xA = (lm << 7) + (kg << 6) + (lg << 4);
      xA ^= ((xA >> 7) & 7) << 4;
      short8 a = *(const short8*)(base + xA);
#pragma unroll
      for (int ti = 0; ti < 3; ++ti) {
        int tile = wv + ti*4;                   // wave wv owns tiles wv, wv+4, wv+8
        if (tile < 9) {
          int xB = ((16 + tile*16 + lm) << 7) + (kg << 6) + (lg << 4);
          xB ^= ((xB >> 7) & 7) << 4;
          short8 b = *(const short8*)(base + xB);
          acc[ti] = __builtin_amdgcn_mfma_f32_16x16x32_bf16(a, b, acc[ti], 0, 0, 0);
        }
      }
    }
  };

  stage(0, 0);
  stage(1, 1);
  for (int s = 0; s < 32; ++s) {
    int p = s % 3;
    if (s < 30) {
      stage((s + 2) % 3, s + 2);
      asm volatile("s_waitcnt vmcnt(10)" ::: "memory");  // step s's 5 loads done
    } else if (s == 30) {
      asm volatile("s_waitcnt vmcnt(5)" ::: "memory");
    } else {
      asm volatile("s_waitcnt vmcnt(0)" ::: "memory");
    }
    __builtin_amdgcn_s_barrier();
    asm volatile("" ::: "memory");
    compute(p);
    asm volatile("" ::: "memory");
    __builtin_amdgcn_s_barrier();  // protect buf (s%3) from overwrite at s+1's stage
  }

#pragma unroll
  for (int ti = 0; ti < 3; ++ti) {
    int tile = wv + ti*4;
    if (tile < 9) {
      int j = j0 + tile*16 + lm;
      int m = m0 + lg*4;
      *(f32x4*)(Cf + (long)j*KPAD + m) = acc[ti];
      if (writeCb) {
        short4_t hv;
#pragma unroll
        for (int q = 0; q < 4; ++q)
          hv[q] = (m + q < N_) ? (short)f2b(acc[ti][q]) : (short)0;
        *(short4_t*)(Cb + (long)j*KPAD + m) = hv;
      }
    }
  }
}

// ---------------------------------------------------------------------------
// xesP[seg][b][e2] = sum_{e1 in seg} u[b,e1]*hodge[e1,e2]  (plain stores,
// no atomics; "+v" folded into k_redxes). grid (12 e2-chunks, SEGS).
// ---------------------------------------------------------------------------
__global__ void k_hodge(const float* __restrict__ u, const float* __restrict__ hodge,
                        float* __restrict__ xesP) {
  const int t = threadIdx.x;
  const int e2 = blockIdx.x*256 + t;
  const int seg = blockIdx.y;
  const int e1a = seg*ECH;
  __shared__ float ul[ECH*16];
  for (int idx = t; idx < ECH*16; idx += 256) {
    int bb = idx / ECH, ee = idx - bb*ECH;
    ul[ee*16 + bb] = u[bb*E_ + e1a + ee];
  }
  __syncthreads();
  if (e2 >= E_) return;
  float acc[16] = {};
  for (int ee = 0; ee < ECH; ee += 8) {
    float h[8];
#pragma unroll
    for (int q = 0; q < 8; ++q) h[q] = hodge[(long)(e1a + ee + q)*E_ + e2];
#pragma unroll
    for (int q = 0; q < 8; ++q) {
#pragma unroll
      for (int g4 = 0; g4 < 4; ++g4) {
        f32x4 u4 = *(const f32x4*)&ul[(ee + q)*16 + g4*4];
        acc[g4*4+0] += u4.x*h[q];
        acc[g4*4+1] += u4.y*h[q];
        acc[g4*4+2] += u4.z*h[q];
        acc[g4*4+3] += u4.w*h[q];
      }
    }
  }
#pragma unroll
  for (int bb = 0; bb < 16; ++bb)
    xesP[((long)seg*16 + bb)*E_ + e2] = acc[bb];
}

// xes[b,e] = sum_seg xesP[seg][b][e] + v[b,e]
__global__ void k_redxes(const float* __restrict__ xesP, const float* __restrict__ v,
                         float* __restrict__ xes) {
  int idx = blockIdx.x*256 + threadIdx.x;
  if (idx >= B_*E_) return;
  int b = idx / E_, e = idx - b*E_;
  float s = v[idx];
#pragma unroll
  for (int q = 0; q < SEGS; ++q) s += xesP[((long)q*16 + b)*E_ + e];
  xes[idx] = s;
}

// ---------------------------------------------------------------------------
// xenP[q][b][n] = (1/3) * sum_{e in quarter q} xes[b,e]*inc[n,e]
// (plain stores; the 4 partials summed in k_tail). grid (125, 4).
// ---------------------------------------------------------------------------
__global__ void k_inc(const float* __restrict__ xes, const float* __restrict__ inc,
                      float* __restrict__ xenP) {
  const int t = threadIdx.x;
  const int b = t & 15, nl = t >> 4;
  const int nb0 = blockIdx.x*16;
  const int n = nb0 + nl;
  const int ea = blockIdx.y*750;
  __shared__ float il[16][252];
  float acc = 0.f;
  for (int c3 = 0; c3 < 3; ++c3) {
    int ec = ea + c3*250;
    __syncthreads();
    for (int idx = t; idx < 16*250; idx += 256) {
      int rr = idx / 250, ee = idx - rr*250;
      il[rr][ee] = inc[(long)(nb0 + rr)*E_ + ec + ee];
    }
    __syncthreads();
    const float* xr = xes + b*E_ + ec;
    for (int ee = 0; ee < 248; ee += 4) {
      f32x2 a0 = *(const f32x2*)(xr + ee);
      f32x2 a1 = *(const f32x2*)(xr + ee + 2);
      f32x4 i4 = *(const f32x4*)&il[nl][ee];
      acc += a0.x*i4.x + a0.y*i4.y + a1.x*i4.z + a1.y*i4.w;
    }
    acc += xr[248]*il[nl][248] + xr[249]*il[nl][249];
  }
  xenP[((long)blockIdx.y*16 + b)*N_ + n] = acc*(1.f/3.f);
}

// ---------------------------------------------------------------------------
// Fused output tail:
//  blocks [0,500): diffusion epilogue (o<64): 4 nodes/block, ne in regs,
//    xs from C32a/C32b f32 (L2), W in LDS bf16 (bias = ki 51 row).
//  blocks [500,2500): o in [64,256): one block per node, 192 active threads.
//  xen read as sum of 4 k_inc partials.
// ---------------------------------------------------------------------------
#define NPC 4
__global__ __launch_bounds__(256) void k_tail(const float* __restrict__ x,
                          const float* __restrict__ C32a,
                          const float* __restrict__ C32b,
                          const float* __restrict__ ne,
                          const float* __restrict__ wp,
                          const float* __restrict__ bp,
                          const float* __restrict__ wwt, const float* __restrict__ wws,
                          const float* __restrict__ zfc, const float* __restrict__ gnnb,
                          const float* __restrict__ g, const float* __restrict__ xw,
                          const float* __restrict__ xenP,
                          float* __restrict__ out) {
  __shared__ ushort_t W_l[NPC*52*64];
  __shared__ float xs_l[NPC*52*20];
  __shared__ float ne_s[16];
  const int t = threadIdx.x;
  if (blockIdx.x < 500) {
    const int n0 = blockIdx.x*NPC;
    const int lane = t & 63, wv = t >> 6;
    float nev[NPC][16];
#pragma unroll
    for (int p = 0; p < NPC; ++p)
#pragma unroll
      for (int q = 0; q < 4; ++q)
        *(f32x4*)&nev[p][q*4] = *(const f32x4*)(ne + (n0 + p)*D_ + q*4);
    for (int idx = t; idx < 52*64; idx += 256) {
      int ki = idx >> 6, o = idx & 63;
      float a[NPC] = {};
#pragma unroll
      for (int d = 0; d < 16; ++d) {
        float w = (ki < KI_) ? wp[d*3264 + idx] : bp[d*256 + o];
#pragma unroll
        for (int p = 0; p < NPC; ++p) a[p] += nev[p][d]*w;
      }
#pragma unroll
      for (int p = 0; p < NPC; ++p) W_l[p*3328 + idx] = f2b(a[p]);
    }
    for (int idx = t; idx < KI_*64; idx += 256) {
      int ki = idx >> 6;
      int b = (idx >> 2) & 15, p = idx & 3;
      int k = ki / C_, cc = ki - k*C_;
      int n = n0 + p;
      float v;
      if (k == 0)      v = x[(b*N_ + n)*C_ + cc];
      else if (k == 1) v = C32a[(long)(b*C_ + cc)*KPAD + n];
      else             v = C32b[(long)(b*C_ + cc)*KPAD + n];
      xs_l[p*1040 + ki*20 + b] = v;
    }
    if (t < 64) xs_l[(t & 3)*1040 + KI_*20 + (t >> 2)] = 1.0f;
    __syncthreads();
    const int o = lane, bg = wv;
#pragma unroll
    for (int p = 0; p < NPC; ++p) {
      f32x4 acc = {0.f,0.f,0.f,0.f};
      for (int ki = 0; ki < 52; ++ki) {
        float w = b2f_u(W_l[p*3328 + ki*64 + o]);
        f32x4 xs4 = *(const f32x4*)&xs_l[p*1040 + ki*20 + bg*4];
        acc += xs4 * w;
      }
#pragma unroll
      for (int j = 0; j < 4; ++j)
        out[((long)((bg*4 + j)*N_ + n0 + p))*O_ + o] = acc[j];
    }
  } else {
    const int n = blockIdx.x - 500;
    if (t < 16) ne_s[t] = ne[n*16 + t];
    __syncthreads();
    if (t >= 192) return;
    const int o = 64 + t;
    float bias = 0.f;
#pragma unroll
    for (int d = 0; d < 16; ++d) bias += ne_s[d]*bp[d*256 + o];
    float w = 0.f, gi = 0.f, gb = 0.f;
    int q = 0;
    if (t < 32) {
      int flat = n*32 + t;          // reshape (B,32,N)->(B,N,32)
      q = flat / N_;
      int i = flat - q*N_;
      gi = g[i]; gb = gnnb[i];
    } else if (t < 160) {
#pragma unroll
      for (int d = 0; d < 16; ++d) w += ne_s[d]*wwt[d*128 + (t - 32)];
    } else {
#pragma unroll
      for (int d = 0; d < 16; ++d) w += ne_s[d]*wws[d*32 + (t - 160)];
    }
    for (int b = 0; b < B_; ++b) {
      float val;
      if (t < 32) {
        float z = zfc[b*32 + q]*gi + gb;
        val = z > 0.f ? z : 0.f;
      } else if (t < 160) {
        val = xw[b*N_ + n]*w;
      } else {
        float xe = xenP[b*N_ + n] + xenP[(16 + b)*N_ + n]
                 + xenP[(32 + b)*N_ + n] + xenP[(48 + b)*N_ + n];
        val = xe*w;
      }
      out[((long)(b*N_ + n))*O_ + o] = val + bias;
    }
  }
}

extern "C" void kernel_launch(void* const* d_in, const int* in_sizes, int n_in,
                              void* d_out, int out_size, void* d_ws, size_t ws_size,
                              hipStream_t stream) {
  const float* x     = (const float*)d_in[0];
  const float* xwin  = (const float*)d_in[1];
  const float* ne    = (const float*)d_in[2];
  // d_in[3] fixed_adj == 0 -> softmax branch (adj d_in[4] unused)
  const int*   stay  = (const int*)d_in[5];
  const int*   jc    = (const int*)d_in[6];
  const float* zfc   = (const float*)d_in[7];
  const float* hodge = (const float*)d_in[8];
  const float* xew   = (const float*)d_in[9];
  const float* inc   = (const float*)d_in[10];
  const float* wp    = (const float*)d_in[11];
  const float* wws   = (const float*)d_in[12];
  const float* wwt   = (const float*)d_in[13];
  const float* bp    = (const float*)d_in[14];
  const float* Tp    = (const float*)d_in[15];
  const float* lw    = (const float*)d_in[16];
  const float* lb    = (const float*)d_in[17];
  const float* gw    = (const float*)d_in[18];
  const float* gnnb  = (const float*)d_in[19];
  const int*   bidx  = (const int*)d_in[20];
  float* out = (float*)d_out;

  // d_ws: only what k_tail (the out-writer) reads, plus small intermediates.
  char* wsb = (char*)d_ws;
  float*    C32a = (float*)(wsb);                 // 288*2048*4 = 2,359,296
  float*    C32b = (float*)(wsb + 2359296);       // 2,359,296
  // BT1 aliases the first half of C32b: BT1 dead after k_mm2 #1; C32b is
  // written by k_mm2 #2, which runs after. Stream-ordered, safe.
  ushort_t* BT1  = (ushort_t*)(wsb + 2359296);    // 1,179,648
  float* u    = (float*)(wsb + 4718592);          // 192,000
  float* v    = (float*)(wsb + 4910592);          // 192,000
  float* xes  = (float*)(wsb + 5102592);          // 192,000
  float* xw   = (float*)(wsb + 5294592);          // 128,000
  float* g    = (float*)(wsb + 5422592);          //   8,000
  float* xenP = (float*)(wsb + 5430592);          // 512,000 -> total 5,942,592 B

  // d_out as scratch for buffers dead before k_tail (k_tail writes every
  // output element, and reads none of these):
  char* ob = (char*)d_out;
  ushort_t* S    = (ushort_t*)(ob);               // [2048][2048] bf16 = 8,388,608
  ushort_t* BT2  = (ushort_t*)(ob + 8388608);     // 1,179,648
  float*    xesP = (float*)(ob + 9568256);        // SEGS*16*E_*4 = 2,880,000 -> 12,448,256 (< 32.7 MB)

  k_small<<<2601, 256, 0, stream>>>(xew, bidx, lw, lb, jc, u, v,
                                    xwin, Tp, xw, gw, g, x, BT1);
  k_S<<<2048, 256, 0, stream>>>(ne, stay, S);
  k_mm2<<<dim3(128,2), 256, 0, stream>>>(S, BT1, C32a, BT2, 1);      // xs1^T (f32 + bf16)
  k_mm2<<<dim3(128,2), 256, 0, stream>>>(S, BT2, C32b, nullptr, 0);  // xs2^T (f32)
  k_hodge<<<dim3(12, SEGS), 256, 0, stream>>>(u, hodge, xesP);
  k_redxes<<<188, 256, 0, stream>>>(xesP, v, xes);
  k_inc<<<dim3(125, 4), 256, 0, stream>>>(xes, inc, xenP);
  k_tail<<<2500, 256, 0, stream>>>(x, C32a, C32b, ne, wp, bp, wwt, wws,
                                   zfc, gnnb, g, xw, xenP, out);
}

// Round 2
// 290.109 us; speedup vs baseline: 1.2815x; 1.1002x over previous
//
#include <hip/hip_runtime.h>
#include <hip/hip_bf16.h>

typedef __hip_bfloat16 bf16;
typedef unsigned short ushort_t;
typedef __attribute__((ext_vector_type(8))) short short8;
typedef __attribute__((ext_vector_type(4))) short short4_t;
typedef __attribute__((ext_vector_type(4))) float f32x4;
typedef __attribute__((ext_vector_type(2))) float f32x2;

#define B_ 16
#define N_ 2000
#define E_ 3000
#define C_ 17
#define W_ 12
#define D_ 16
#define O_ 256
#define NB_ 3
#define KPAD 2048  // padded K/m stride (and padded S row stride)
#define KI_ 51     // 3*17 diffusion taps
#define SEGS 25    // k_hodge e1 segments (300 blocks)
#define ECH 120    // e1 chunk per segment (SEGS*ECH = E_, div by 8)
#define EPAD 768   // k_inc e-chunk (4 chunks cover 3000, zero-padded)

static __device__ __forceinline__ ushort_t f2b(float f) {
  bf16 h = __float2bfloat16(f);
  return *reinterpret_cast<ushort_t*>(&h);
}
static __device__ __forceinline__ float b2f_u(ushort_t u) {
  bf16 h = *reinterpret_cast<bf16*>(&u);
  return __bfloat162float(h);
}
__device__ __forceinline__ int idxval(const int* p, int i) {
  int iv = p[i];
  if (iv >= 0 && iv < 1000000) return iv;
  return (int)__int_as_float(iv);
}

// ---------------------------------------------------------------------------
// S = softmax(relu(ne@ne^T), diag=stay) rows -> bf16, row stride KPAD=2048,
// cols [2000,2048) zero, rows [2000,2048) zero (grid 2048). ne staged via LDS.
// ---------------------------------------------------------------------------
__global__ void k_S(const float* __restrict__ ne, const int* __restrict__ stay,
                    ushort_t* __restrict__ S) {
  const int i = blockIdx.x;
  const int t = threadIdx.x;
  if (i >= N_) {  // uniform per-block branch, no syncthreads on this path
#pragma unroll
    for (int it = 0; it < 8; ++it) S[(long)i*KPAD + t + it*256] = 0;
    return;
  }
  __shared__ float ne_l[512*20];
  __shared__ float reds[4];
  f32x4 nei[4];
#pragma unroll
  for (int q = 0; q < 4; ++q) nei[q] = *(const f32x4*)(ne + i*16 + q*4);
  const float stayf = (float)(*stay);
  float vals[8];
  float s = 0.f;
  for (int c = 0; c < 4; ++c) {
    __syncthreads();
#pragma unroll
    for (int u = 0; u < 8; ++u) {
      int unit = t + u*256;
      int row = unit >> 2, dq = unit & 3;
      int gj = c*512 + row;
      f32x4 v = {0.f,0.f,0.f,0.f};
      if (gj < N_) v = *(const f32x4*)(ne + gj*16 + dq*4);
      *(f32x4*)(ne_l + row*20 + dq*4) = v;
    }
    __syncthreads();
#pragma unroll
    for (int r = 0; r < 2; ++r) {
      int row_l = t + r*256;
      int j = c*512 + row_l;
      float e = 0.f;
      if (j < N_) {
        f32x4 a4 = {0.f,0.f,0.f,0.f};
#pragma unroll
        for (int q = 0; q < 4; ++q) a4 += nei[q] * (*(const f32x4*)(ne_l + row_l*20 + q*4));
        float dot = a4.x + a4.y + a4.z + a4.w;
        float v = dot > 0.f ? dot : 0.f;
        if (j == i) v = stayf;
        e = __expf(v);
        s += e;
      }
      vals[2*c + r] = e;
    }
  }
#pragma unroll
  for (int off = 32; off > 0; off >>= 1) s += __shfl_xor(s, off, 64);
  if ((t & 63) == 0) reds[t >> 6] = s;
  __syncthreads();
  s = reds[0] + reds[1] + reds[2] + reds[3];
  const float inv = 1.f/s;
#pragma unroll
  for (int it = 0; it < 8; ++it) {
    int j = t + it*256;
    S[(long)i*KPAD + j] = f2b(vals[it]*inv);  // vals==0 for j>=N_ -> stores 0
  }
}

// ---------------------------------------------------------------------------
// Fused independent small kernels (block-range dispatch):
//  [0,188) u/v; [188,313) xw; [313,2313) g rowsums; [2313,2601) BT1 build
// ---------------------------------------------------------------------------
__global__ void k_small(const float* __restrict__ xew, const int* __restrict__ bidx,
                        const float* __restrict__ lw, const float* __restrict__ lb,
                        const int* __restrict__ jc, float* __restrict__ u,
                        float* __restrict__ v,
                        const float* __restrict__ xwin, const float* __restrict__ Tp,
                        float* __restrict__ xw,
                        const float* __restrict__ gw, float* __restrict__ g,
                        const float* __restrict__ x, ushort_t* __restrict__ BT1) {
  const int bid = blockIdx.x;
  const int t = threadIdx.x;
  if (bid < 188) {
    int idx = bid*256 + t;
    if (idx >= B_*E_) return;
    int b = idx / E_, e = idx - b*E_;
    const float lwf = lw[0], lbf = lb[0];
    float uu = 0.f, vv = 0.f;
#pragma unroll
    for (int f = 0; f < NB_; ++f) {
      int tt = idxval(bidx, f);
      if (tt < 0) tt = 0;
      if (tt >= W_) tt = W_ - 1;
      float val = xew[(b*W_ + tt)*E_ + e]*lwf + lbf;
      uu += val;
      vv += (float)(NB_ - 1 - f)*val;
    }
    u[idx] = uu;
    v[idx] = vv*(float)(*jc);
  } else if (bid < 313) {
    int idx = (bid - 188)*256 + t;
    int b = idx / N_, n = idx - b*N_;
    float s = 0.f;
#pragma unroll
    for (int tt = 0; tt < W_; ++tt) s += xwin[(b*W_ + tt)*N_ + n]*Tp[tt];
    xw[idx] = s;
  } else if (bid < 2313) {
    int i = bid - 313;
    float s = 0.f;
    for (int j = t; j < N_; j += 256) s += gw[(long)i*N_ + j];
#pragma unroll
    for (int off = 32; off > 0; off >>= 1) s += __shfl_xor(s, off, 64);
    __shared__ float red[4];
    if ((t & 63) == 0) red[t >> 6] = s;
    __syncthreads();
    if (t == 0) g[i] = red[0] + red[1] + red[2] + red[3];
  } else {
    int j = bid - 2313;
    int bb = j / C_, cc = j - bb*C_;
#pragma unroll
    for (int uu = 0; uu < 8; ++uu) {
      int n = t + uu*256;
      float vv = 0.f;
      if (bb < B_ && n < N_) vv = x[(bb*N_ + n)*C_ + cc];
      BT1[(long)j*KPAD + n] = f2b(vv);
    }
  }
}

// ---------------------------------------------------------------------------
// MFMA GEMM v2: C[j][m] = sum_k A[m][k]*B[j][k], K=2048 (zero-padded), no
// split-K, no atomics. Grid (128 m-tiles of 16, 2 j-halves of 144); 256 thr.
// Triple-buffered global_load_lds (16B) staging; counted vmcnt + raw
// s_barrier so prefetch loads stay in flight across barriers. LDS linear
// with XOR involution swizzle x^=((x>>7)&7)<<4 applied to BOTH the global
// source address and the ds_read address (bank-conflict-free b128 reads).
// Epilogue: f32x4 store to Cf; optionally bf16 store to Cb (pad m>=2000 = 0).
// ---------------------------------------------------------------------------
__global__ __launch_bounds__(256) void k_mm2(const ushort_t* __restrict__ A,
                                             const ushort_t* __restrict__ BT,
                                             float* __restrict__ Cf,
                                             ushort_t* __restrict__ Cb,
                                             int writeCb) {
  __shared__ ushort_t lds[3][10240];  // 3 x 20480 B: [0,2048)=A 16x128B, [2048,20480)=B 144x128B
  const int t = threadIdx.x;
  const int m0 = blockIdx.x * 16;
  const int j0 = blockIdx.y * 144;
  const int wv = t >> 6, lane = t & 63;
  const int lm = lane & 15, lg = lane >> 4;
  const char* gA = (const char*)A + (size_t)m0 * (KPAD*2);
  const char* gB = (const char*)BT + (size_t)j0 * (KPAD*2);

  f32x4 acc[3];
#pragma unroll
  for (int q = 0; q < 3; ++q) acc[q] = (f32x4){0.f,0.f,0.f,0.f};

  auto stage = [&](int p, int s) {
    const long kb = (long)s * 128;  // 64 bf16 per K-step
#pragma unroll
    for (int u = 0; u < 5; ++u) {
      int x = (u*256 + t) << 4;                 // linear LDS byte this lane fills
      int y = x ^ (((x >> 7) & 7) << 4);        // involution: fetch swizzled source
      int r = y >> 7, c = y & 127;              // region row (A:0..15, B:16..159), col bytes
      const char* gp = (r < 16) ? gA + (long)r*(KPAD*2) + kb + c
                                : gB + (long)(r-16)*(KPAD*2) + kb + c;
      __builtin_amdgcn_global_load_lds(
          (const __attribute__((address_space(1))) void*)gp,
          (__attribute__((address_space(3))) void*)(&lds[p][u*2048 + wv*512]),
          16, 0, 0);
    }
  };

  auto compute = [&](int p) {
    const char* base = (const char*)&lds[p][0];
#pragma unroll
    for (int kg = 0; kg < 2; ++kg) {
      int xA = (lm << 7) + (kg << 6) + (lg << 4);
      xA ^= ((xA >> 7) & 7) << 4;
      short8 a = *(const short8*)(base + xA);
#pragma unroll
      for (int ti = 0; ti < 3; ++ti) {
        int tile = wv + ti*4;                   // wave wv owns tiles wv, wv+4, wv+8
        if (tile < 9) {
          int xB = ((16 + tile*16 + lm) << 7) + (kg << 6) + (lg << 4);
          xB ^= ((xB >> 7) & 7) << 4;
          short8 b = *(const short8*)(base + xB);
          acc[ti] = __builtin_amdgcn_mfma_f32_16x16x32_bf16(a, b, acc[ti], 0, 0, 0);
        }
      }
    }
  };

  stage(0, 0);
  stage(1, 1);
  for (int s = 0; s < 32; ++s) {
    int p = s % 3;
    if (s < 30) {
      stage((s + 2) % 3, s + 2);
      asm volatile("s_waitcnt vmcnt(10)" ::: "memory");  // step s's 5 loads done
    } else if (s == 30) {
      asm volatile("s_waitcnt vmcnt(5)" ::: "memory");
    } else {
      asm volatile("s_waitcnt vmcnt(0)" ::: "memory");
    }
    __builtin_amdgcn_s_barrier();
    asm volatile("" ::: "memory");
    compute(p);
    asm volatile("" ::: "memory");
    __builtin_amdgcn_s_barrier();  // protect buf (s%3) from overwrite at s+1's stage
  }

#pragma unroll
  for (int ti = 0; ti < 3; ++ti) {
    int tile = wv + ti*4;
    if (tile < 9) {
      int j = j0 + tile*16 + lm;
      int m = m0 + lg*4;
      *(f32x4*)(Cf + (long)j*KPAD + m) = acc[ti];
      if (writeCb) {
        short4_t hv;
#pragma unroll
        for (int q = 0; q < 4; ++q)
          hv[q] = (m + q < N_) ? (short)f2b(acc[ti][q]) : (short)0;
        *(short4_t*)(Cb + (long)j*KPAD + m) = hv;
      }
    }
  }
}

// ---------------------------------------------------------------------------
// xesP[seg][b][e2] = sum_{e1 in seg} u[b,e1]*hodge[e1,e2]  (plain stores,
// no atomics; "+v" folded into k_redxes). grid (12 e2-chunks, SEGS=25).
// ---------------------------------------------------------------------------
__global__ void k_hodge(const float* __restrict__ u, const float* __restrict__ hodge,
                        float* __restrict__ xesP) {
  const int t = threadIdx.x;
  const int e2 = blockIdx.x*256 + t;
  const int seg = blockIdx.y;
  const int e1a = seg*ECH;
  __shared__ float ul[ECH*16];
  for (int idx = t; idx < ECH*16; idx += 256) {
    int bb = idx / ECH, ee = idx - bb*ECH;
    ul[ee*16 + bb] = u[bb*E_ + e1a + ee];
  }
  __syncthreads();
  if (e2 >= E_) return;
  float acc[16] = {};
  for (int ee = 0; ee < ECH; ee += 8) {
    float h[8];
#pragma unroll
    for (int q = 0; q < 8; ++q) h[q] = hodge[(long)(e1a + ee + q)*E_ + e2];
#pragma unroll
    for (int q = 0; q < 8; ++q) {
#pragma unroll
      for (int g4 = 0; g4 < 4; ++g4) {
        f32x4 u4 = *(const f32x4*)&ul[(ee + q)*16 + g4*4];
        acc[g4*4+0] += u4.x*h[q];
        acc[g4*4+1] += u4.y*h[q];
        acc[g4*4+2] += u4.z*h[q];
        acc[g4*4+3] += u4.w*h[q];
      }
    }
  }
#pragma unroll
  for (int bb = 0; bb < 16; ++bb)
    xesP[((long)seg*16 + bb)*E_ + e2] = acc[bb];
}

// xes[b,e] = sum_seg xesP[seg][b][e] + v[b,e]
__global__ void k_redxes(const float* __restrict__ xesP, const float* __restrict__ v,
                         float* __restrict__ xes) {
  int idx = blockIdx.x*256 + threadIdx.x;
  if (idx >= B_*E_) return;
  int b = idx / E_, e = idx - b*E_;
  float s = v[idx];
#pragma unroll
  for (int q = 0; q < SEGS; ++q) s += xesP[((long)q*16 + b)*E_ + e];
  xes[idx] = s;
}

// ---------------------------------------------------------------------------
// k_inc v3: xenP[cy][b][n] = (1/3)*sum_{e in chunk cy} xes[b,e]*inc[n,e]
// Old version: 500 blocks, 16-way-divergent global xes reads in the inner
// loop -> 46 us latency-bound. New: grid (250 n-tiles of 8, 4 e-chunks of
// 768) = 1000 blocks. xes chunk staged in LDS (48 KB, zero-padded); each
// wave owns 2 n-rows; lanes read inc coalesced f32x4 (1 KB/wave-instr) and
// xes_l per-b as contiguous conflict-free b128; 32 f32 accs/lane; one
// 64-lane butterfly per block. Floors: ~5 us FMA, ~4 us HBM (24 MB inc).
// ---------------------------------------------------------------------------
__global__ __launch_bounds__(256) void k_inc(const float* __restrict__ xes,
                                             const float* __restrict__ inc,
                                             float* __restrict__ xenP) {
  __shared__ float xes_l[16*EPAD];  // 48 KB
  const int t = threadIdx.x;
  const int wv = t >> 6, lane = t & 63;
  const int cy = blockIdx.y;
  const int n0 = blockIdx.x*8;
  // stage xes[:, cy*768 .. +768) -> LDS, zero pad past E_
  for (int i4 = t; i4 < 16*(EPAD/4); i4 += 256) {   // 12 iters
    int row = i4 / (EPAD/4);
    int el = (i4 - row*(EPAD/4)) << 2;
    int e = cy*EPAD + el;
    f32x4 vv = {0.f,0.f,0.f,0.f};
    if (e < E_) vv = *(const f32x4*)(xes + (long)row*E_ + e);
    *(f32x4*)&xes_l[row*EPAD + el] = vv;
  }
  __syncthreads();
  const int na = n0 + wv*2;
  const int nb = na + 1;
  const float* rowA = inc + (long)na*E_ + cy*EPAD;
  const float* rowB = inc + (long)nb*E_ + cy*EPAD;
  float accA[16] = {}, accB[16] = {};
#pragma unroll
  for (int g = 0; g < 3; ++g) {
    int e4 = (g*64 + lane) << 2;
    bool ok = (cy*EPAD + e4) < E_;
    f32x4 ia = {0.f,0.f,0.f,0.f}, ib = {0.f,0.f,0.f,0.f};
    if (ok) { ia = *(const f32x4*)(rowA + e4); ib = *(const f32x4*)(rowB + e4); }
#pragma unroll
    for (int b = 0; b < 16; ++b) {
      f32x4 xs = *(const f32x4*)&xes_l[b*EPAD + e4];
      accA[b] += xs.x*ia.x + xs.y*ia.y + xs.z*ia.z + xs.w*ia.w;
      accB[b] += xs.x*ib.x + xs.y*ib.y + xs.z*ib.z + xs.w*ib.w;
    }
  }
  // cross-lane reduce (all 64 lanes end with the sum)
#pragma unroll
  for (int b = 0; b < 16; ++b) {
#pragma unroll
    for (int off = 32; off > 0; off >>= 1) {
      accA[b] += __shfl_xor(accA[b], off, 64);
      accB[b] += __shfl_xor(accB[b], off, 64);
    }
  }
  // static-index extraction (no scratch), lanes 0-15 -> row na, 16-31 -> nb
  const int bl = lane & 15;
  float oA = 0.f, oB = 0.f;
#pragma unroll
  for (int b = 0; b < 16; ++b)
    if (bl == b) { oA = accA[b]; oB = accB[b]; }
  if (lane < 16)
    xenP[((long)cy*16 + bl)*N_ + na] = oA*(1.f/3.f);
  else if (lane < 32)
    xenP[((long)cy*16 + bl)*N_ + nb] = oB*(1.f/3.f);
}

// ---------------------------------------------------------------------------
// Fused output tail:
//  blocks [0,500): diffusion epilogue (o<64): 4 nodes/block, ne in regs,
//    xs from C32a/C32b f32 (L2), W in LDS bf16 (bias = ki 51 row).
//  blocks [500,2500): o in [64,256): one block per node, 192 active threads.
//  xen read as sum of 4 k_inc partials.
// ---------------------------------------------------------------------------
#define NPC 4
__global__ __launch_bounds__(256) void k_tail(const float* __restrict__ x,
                          const float* __restrict__ C32a,
                          const float* __restrict__ C32b,
                          const float* __restrict__ ne,
                          const float* __restrict__ wp,
                          const float* __restrict__ bp,
                          const float* __restrict__ wwt, const float* __restrict__ wws,
                          const float* __restrict__ zfc, const float* __restrict__ gnnb,
                          const float* __restrict__ g, const float* __restrict__ xw,
                          const float* __restrict__ xenP,
                          float* __restrict__ out) {
  __shared__ ushort_t W_l[NPC*52*64];
  __shared__ float xs_l[NPC*52*20];
  __shared__ float ne_s[16];
  const int t = threadIdx.x;
  if (blockIdx.x < 500) {
    const int n0 = blockIdx.x*NPC;
    const int lane = t & 63, wv = t >> 6;
    float nev[NPC][16];
#pragma unroll
    for (int p = 0; p < NPC; ++p)
#pragma unroll
      for (int q = 0; q < 4; ++q)
        *(f32x4*)&nev[p][q*4] = *(const f32x4*)(ne + (n0 + p)*D_ + q*4);
    for (int idx = t; idx < 52*64; idx += 256) {
      int ki = idx >> 6, o = idx & 63;
      float a[NPC] = {};
#pragma unroll
      for (int d = 0; d < 16; ++d) {
        float w = (ki < KI_) ? wp[d*3264 + idx] : bp[d*256 + o];
#pragma unroll
        for (int p = 0; p < NPC; ++p) a[p] += nev[p][d]*w;
      }
#pragma unroll
      for (int p = 0; p < NPC; ++p) W_l[p*3328 + idx] = f2b(a[p]);
    }
    for (int idx = t; idx < KI_*64; idx += 256) {
      int ki = idx >> 6;
      int b = (idx >> 2) & 15, p = idx & 3;
      int k = ki / C_, cc = ki - k*C_;
      int n = n0 + p;
      float v;
      if (k == 0)      v = x[(b*N_ + n)*C_ + cc];
      else if (k == 1) v = C32a[(long)(b*C_ + cc)*KPAD + n];
      else             v = C32b[(long)(b*C_ + cc)*KPAD + n];
      xs_l[p*1040 + ki*20 + b] = v;
    }
    if (t < 64) xs_l[(t & 3)*1040 + KI_*20 + (t >> 2)] = 1.0f;
    __syncthreads();
    const int o = lane, bg = wv;
#pragma unroll
    for (int p = 0; p < NPC; ++p) {
      f32x4 acc = {0.f,0.f,0.f,0.f};
      for (int ki = 0; ki < 52; ++ki) {
        float w = b2f_u(W_l[p*3328 + ki*64 + o]);
        f32x4 xs4 = *(const f32x4*)&xs_l[p*1040 + ki*20 + bg*4];
        acc += xs4 * w;
      }
#pragma unroll
      for (int j = 0; j < 4; ++j)
        out[((long)((bg*4 + j)*N_ + n0 + p))*O_ + o] = acc[j];
    }
  } else {
    const int n = blockIdx.x - 500;
    if (t < 16) ne_s[t] = ne[n*16 + t];
    __syncthreads();
    if (t >= 192) return;
    const int o = 64 + t;
    float bias = 0.f;
#pragma unroll
    for (int d = 0; d < 16; ++d) bias += ne_s[d]*bp[d*256 + o];
    float w = 0.f, gi = 0.f, gb = 0.f;
    int q = 0;
    if (t < 32) {
      int flat = n*32 + t;          // reshape (B,32,N)->(B,N,32)
      q = flat / N_;
      int i = flat - q*N_;
      gi = g[i]; gb = gnnb[i];
    } else if (t < 160) {
#pragma unroll
      for (int d = 0; d < 16; ++d) w += ne_s[d]*wwt[d*128 + (t - 32)];
    } else {
#pragma unroll
      for (int d = 0; d < 16; ++d) w += ne_s[d]*wws[d*32 + (t - 160)];
    }
    for (int b = 0; b < B_; ++b) {
      float val;
      if (t < 32) {
        float z = zfc[b*32 + q]*gi + gb;
        val = z > 0.f ? z : 0.f;
      } else if (t < 160) {
        val = xw[b*N_ + n]*w;
      } else {
        float xe = xenP[b*N_ + n] + xenP[(16 + b)*N_ + n]
                 + xenP[(32 + b)*N_ + n] + xenP[(48 + b)*N_ + n];
        val = xe*w;
      }
      out[((long)(b*N_ + n))*O_ + o] = val + bias;
    }
  }
}

extern "C" void kernel_launch(void* const* d_in, const int* in_sizes, int n_in,
                              void* d_out, int out_size, void* d_ws, size_t ws_size,
                              hipStream_t stream) {
  const float* x     = (const float*)d_in[0];
  const float* xwin  = (const float*)d_in[1];
  const float* ne    = (const float*)d_in[2];
  // d_in[3] fixed_adj == 0 -> softmax branch (adj d_in[4] unused)
  const int*   stay  = (const int*)d_in[5];
  const int*   jc    = (const int*)d_in[6];
  const float* zfc   = (const float*)d_in[7];
  const float* hodge = (const float*)d_in[8];
  const float* xew   = (const float*)d_in[9];
  const float* inc   = (const float*)d_in[10];
  const float* wp    = (const float*)d_in[11];
  const float* wws   = (const float*)d_in[12];
  const float* wwt   = (const float*)d_in[13];
  const float* bp    = (const float*)d_in[14];
  const float* Tp    = (const float*)d_in[15];
  const float* lw    = (const float*)d_in[16];
  const float* lb    = (const float*)d_in[17];
  const float* gw    = (const float*)d_in[18];
  const float* gnnb  = (const float*)d_in[19];
  const int*   bidx  = (const int*)d_in[20];
  float* out = (float*)d_out;

  // d_ws: only what k_tail (the out-writer) reads, plus small intermediates.
  char* wsb = (char*)d_ws;
  float*    C32a = (float*)(wsb);                 // 288*2048*4 = 2,359,296
  float*    C32b = (float*)(wsb + 2359296);       // 2,359,296
  // BT1 aliases the first half of C32b: BT1 dead after k_mm2 #1; C32b is
  // written by k_mm2 #2, which runs after. Stream-ordered, safe.
  ushort_t* BT1  = (ushort_t*)(wsb + 2359296);    // 1,179,648
  float* u    = (float*)(wsb + 4718592);          // 192,000
  float* v    = (float*)(wsb + 4910592);          // 192,000
  float* xes  = (float*)(wsb + 5102592);          // 192,000
  float* xw   = (float*)(wsb + 5294592);          // 128,000
  float* g    = (float*)(wsb + 5422592);          //   8,000
  float* xenP = (float*)(wsb + 5430592);          // 512,000 -> total 5,942,592 B

  // d_out as scratch for buffers dead before k_tail (k_tail writes every
  // output element, and reads none of these):
  char* ob = (char*)d_out;
  ushort_t* S    = (ushort_t*)(ob);               // [2048][2048] bf16 = 8,388,608
  ushort_t* BT2  = (ushort_t*)(ob + 8388608);     // 1,179,648
  float*    xesP = (float*)(ob + 9568256);        // SEGS*16*E_*4 = 4,800,000 -> 14,368,256 (< 32.7 MB)

  k_small<<<2601, 256, 0, stream>>>(xew, bidx, lw, lb, jc, u, v,
                                    xwin, Tp, xw, gw, g, x, BT1);
  k_S<<<2048, 256, 0, stream>>>(ne, stay, S);
  k_mm2<<<dim3(128,2), 256, 0, stream>>>(S, BT1, C32a, BT2, 1);      // xs1^T (f32 + bf16)
  k_mm2<<<dim3(128,2), 256, 0, stream>>>(S, BT2, C32b, nullptr, 0);  // xs2^T (f32)
  k_hodge<<<dim3(12, SEGS), 256, 0, stream>>>(u, hodge, xesP);
  k_redxes<<<188, 256, 0, stream>>>(xesP, v, xes);
  k_inc<<<dim3(250, 4), 256, 0, stream>>>(xes, inc, xenP);
  k_tail<<<2500, 256, 0, stream>>>(x, C32a, C32b, ne, wp, bp, wwt, wws,
                                   zfc, gnnb, g, xw, xenP, out);
}

// Round 4
// 289.050 us; speedup vs baseline: 1.2862x; 1.0037x over previous
//
#include <hip/hip_runtime.h>
#include <hip/hip_bf16.h>

typedef __hip_bfloat16 bf16;
typedef unsigned short ushort_t;
typedef __attribute__((ext_vector_type(8))) short short8;
typedef __attribute__((ext_vector_type(4))) short short4_t;
typedef __attribute__((ext_vector_type(4))) float f32x4;
typedef __attribute__((ext_vector_type(2))) float f32x2;

#define B_ 16
#define N_ 2000
#define E_ 3000
#define C_ 17
#define W_ 12
#define D_ 16
#define O_ 256
#define NB_ 3
#define KPAD 2048  // padded K/m stride (and padded S row stride)
#define KI_ 51     // 3*17 diffusion taps
#define SEGS 25    // k_hodge e1 segments (300 blocks)
#define ECH 120    // e1 chunk per segment (SEGS*ECH = E_, div by 8)
#define EPAD 768   // k_inc e-chunk (4 chunks cover 3000, zero-padded)

static __device__ __forceinline__ ushort_t f2b(float f) {
  bf16 h = __float2bfloat16(f);
  return *reinterpret_cast<ushort_t*>(&h);
}
static __device__ __forceinline__ float b2f_u(ushort_t u) {
  bf16 h = *reinterpret_cast<bf16*>(&u);
  return __bfloat162float(h);
}
__device__ __forceinline__ int idxval(const int* p, int i) {
  int iv = p[i];
  if (iv >= 0 && iv < 1000000) return iv;
  return (int)__int_as_float(iv);
}

// ---------------------------------------------------------------------------
// S = softmax(relu(ne@ne^T), diag=stay) rows -> bf16, row stride KPAD=2048,
// cols [2000,2048) zero, rows [2000,2048) zero (grid 2048). ne staged via LDS.
// ---------------------------------------------------------------------------
__global__ void k_S(const float* __restrict__ ne, const int* __restrict__ stay,
                    ushort_t* __restrict__ S) {
  const int i = blockIdx.x;
  const int t = threadIdx.x;
  if (i >= N_) {  // uniform per-block branch, no syncthreads on this path
#pragma unroll
    for (int it = 0; it < 8; ++it) S[(long)i*KPAD + t + it*256] = 0;
    return;
  }
  __shared__ float ne_l[512*20];
  __shared__ float reds[4];
  f32x4 nei[4];
#pragma unroll
  for (int q = 0; q < 4; ++q) nei[q] = *(const f32x4*)(ne + i*16 + q*4);
  const float stayf = (float)(*stay);
  float vals[8];
  float s = 0.f;
  for (int c = 0; c < 4; ++c) {
    __syncthreads();
#pragma unroll
    for (int u = 0; u < 8; ++u) {
      int unit = t + u*256;
      int row = unit >> 2, dq = unit & 3;
      int gj = c*512 + row;
      f32x4 v = {0.f,0.f,0.f,0.f};
      if (gj < N_) v = *(const f32x4*)(ne + gj*16 + dq*4);
      *(f32x4*)(ne_l + row*20 + dq*4) = v;
    }
    __syncthreads();
#pragma unroll
    for (int r = 0; r < 2; ++r) {
      int row_l = t + r*256;
      int j = c*512 + row_l;
      float e = 0.f;
      if (j < N_) {
        f32x4 a4 = {0.f,0.f,0.f,0.f};
#pragma unroll
        for (int q = 0; q < 4; ++q) a4 += nei[q] * (*(const f32x4*)(ne_l + row_l*20 + q*4));
        float dot = a4.x + a4.y + a4.z + a4.w;
        float v = dot > 0.f ? dot : 0.f;
        if (j == i) v = stayf;
        e = __expf(v);
        s += e;
      }
      vals[2*c + r] = e;
    }
  }
#pragma unroll
  for (int off = 32; off > 0; off >>= 1) s += __shfl_xor(s, off, 64);
  if ((t & 63) == 0) reds[t >> 6] = s;
  __syncthreads();
  s = reds[0] + reds[1] + reds[2] + reds[3];
  const float inv = 1.f/s;
#pragma unroll
  for (int it = 0; it < 8; ++it) {
    int j = t + it*256;
    S[(long)i*KPAD + j] = f2b(vals[it]*inv);  // vals==0 for j>=N_ -> stores 0
  }
}

// ---------------------------------------------------------------------------
// Fused independent small kernels (block-range dispatch):
//  [0,188) u/v; [188,313) xw; [313,2313) g rowsums; [2313,2601) BT1 build
// ---------------------------------------------------------------------------
__global__ void k_small(const float* __restrict__ xew, const int* __restrict__ bidx,
                        const float* __restrict__ lw, const float* __restrict__ lb,
                        const int* __restrict__ jc, float* __restrict__ u,
                        float* __restrict__ v,
                        const float* __restrict__ xwin, const float* __restrict__ Tp,
                        float* __restrict__ xw,
                        const float* __restrict__ gw, float* __restrict__ g,
                        const float* __restrict__ x, ushort_t* __restrict__ BT1) {
  const int bid = blockIdx.x;
  const int t = threadIdx.x;
  if (bid < 188) {
    int idx = bid*256 + t;
    if (idx >= B_*E_) return;
    int b = idx / E_, e = idx - b*E_;
    const float lwf = lw[0], lbf = lb[0];
    float uu = 0.f, vv = 0.f;
#pragma unroll
    for (int f = 0; f < NB_; ++f) {
      int tt = idxval(bidx, f);
      if (tt < 0) tt = 0;
      if (tt >= W_) tt = W_ - 1;
      float val = xew[(b*W_ + tt)*E_ + e]*lwf + lbf;
      uu += val;
      vv += (float)(NB_ - 1 - f)*val;
    }
    u[idx] = uu;
    v[idx] = vv*(float)(*jc);
  } else if (bid < 313) {
    int idx = (bid - 188)*256 + t;
    int b = idx / N_, n = idx - b*N_;
    float s = 0.f;
#pragma unroll
    for (int tt = 0; tt < W_; ++tt) s += xwin[(b*W_ + tt)*N_ + n]*Tp[tt];
    xw[idx] = s;
  } else if (bid < 2313) {
    int i = bid - 313;
    float s = 0.f;
    for (int j = t; j < N_; j += 256) s += gw[(long)i*N_ + j];
#pragma unroll
    for (int off = 32; off > 0; off >>= 1) s += __shfl_xor(s, off, 64);
    __shared__ float red[4];
    if ((t & 63) == 0) red[t >> 6] = s;
    __syncthreads();
    if (t == 0) g[i] = red[0] + red[1] + red[2] + red[3];
  } else {
    int j = bid - 2313;
    int bb = j / C_, cc = j - bb*C_;
#pragma unroll
    for (int uu = 0; uu < 8; ++uu) {
      int n = t + uu*256;
      float vv = 0.f;
      if (bb < B_ && n < N_) vv = x[(bb*N_ + n)*C_ + cc];
      BT1[(long)j*KPAD + n] = f2b(vv);
    }
  }
}

// ---------------------------------------------------------------------------
// MFMA GEMM v2: C[j][m] = sum_k A[m][k]*B[j][k], K=2048 (zero-padded), no
// split-K, no atomics. Grid (128 m-tiles of 16, 2 j-halves of 144); 256 thr.
// Triple-buffered global_load_lds (16B) staging; counted vmcnt + raw
// s_barrier so prefetch loads stay in flight across barriers. LDS linear
// with XOR involution swizzle x^=((x>>7)&7)<<4 applied to BOTH the global
// source address and the ds_read address (bank-conflict-free b128 reads).
// Epilogue: f32x4 store to Cf; optionally bf16 store to Cb (pad m>=2000 = 0).
// ---------------------------------------------------------------------------
__global__ __launch_bounds__(256) void k_mm2(const ushort_t* __restrict__ A,
                                             const ushort_t* __restrict__ BT,
                                             float* __restrict__ Cf,
                                             ushort_t* __restrict__ Cb,
                                             int writeCb) {
  __shared__ ushort_t lds[3][10240];  // 3 x 20480 B: [0,2048)=A 16x128B, [2048,20480)=B 144x128B
  const int t = threadIdx.x;
  const int m0 = blockIdx.x * 16;
  const int j0 = blockIdx.y * 144;
  const int wv = t >> 6, lane = t & 63;
  const int lm = lane & 15, lg = lane >> 4;
  const char* gA = (const char*)A + (size_t)m0 * (KPAD*2);
  const char* gB = (const char*)BT + (size_t)j0 * (KPAD*2);

  f32x4 acc[3];
#pragma unroll
  for (int q = 0; q < 3; ++q) acc[q] = (f32x4){0.f,0.f,0.f,0.f};

  auto stage = [&](int p, int s) {
    const long kb = (long)s * 128;  // 64 bf16 per K-step
#pragma unroll
    for (int u = 0; u < 5; ++u) {
      int x = (u*256 + t) << 4;                 // linear LDS byte this lane fills
      int y = x ^ (((x >> 7) & 7) << 4);        // involution: fetch swizzled source
      int r = y >> 7, c = y & 127;              // region row (A:0..15, B:16..159), col bytes
      const char* gp = (r < 16) ? gA + (long)r*(KPAD*2) + kb + c
                                : gB + (long)(r-16)*(KPAD*2) + kb + c;
      __builtin_amdgcn_global_load_lds(
          (const __attribute__((address_space(1))) void*)gp,
          (__attribute__((address_space(3))) void*)(&lds[p][u*2048 + wv*512]),
          16, 0, 0);
    }
  };

  auto compute = [&](int p) {
    const char* base = (const char*)&lds[p][0];
#pragma unroll
    for (int kg = 0; kg < 2; ++kg) {
      int xA = (lm << 7) + (kg << 6) + (lg << 4);
      xA ^= ((xA >> 7) & 7) << 4;
      short8 a = *(const short8*)(base + xA);
#pragma unroll
      for (int ti = 0; ti < 3; ++ti) {
        int tile = wv + ti*4;                   // wave wv owns tiles wv, wv+4, wv+8
        if (tile < 9) {
          int xB = ((16 + tile*16 + lm) << 7) + (kg << 6) + (lg << 4);
          xB ^= ((xB >> 7) & 7) << 4;
          short8 b = *(const short8*)(base + xB);
          acc[ti] = __builtin_amdgcn_mfma_f32_16x16x32_bf16(a, b, acc[ti], 0, 0, 0);
        }
      }
    }
  };

  stage(0, 0);
  stage(1, 1);
  for (int s = 0; s < 32; ++s) {
    int p = s % 3;
    if (s < 30) {
      stage((s + 2) % 3, s + 2);
      asm volatile("s_waitcnt vmcnt(10)" ::: "memory");  // step s's 5 loads done
    } else if (s == 30) {
      asm volatile("s_waitcnt vmcnt(5)" ::: "memory");
    } else {
      asm volatile("s_waitcnt vmcnt(0)" ::: "memory");
    }
    __builtin_amdgcn_s_barrier();
    asm volatile("" ::: "memory");
    compute(p);
    asm volatile("" ::: "memory");
    __builtin_amdgcn_s_barrier();  // protect buf (s%3) from overwrite at s+1's stage
  }

#pragma unroll
  for (int ti = 0; ti < 3; ++ti) {
    int tile = wv + ti*4;
    if (tile < 9) {
      int j = j0 + tile*16 + lm;
      int m = m0 + lg*4;
      *(f32x4*)(Cf + (long)j*KPAD + m) = acc[ti];
      if (writeCb) {
        short4_t hv;
#pragma unroll
        for (int q = 0; q < 4; ++q)
          hv[q] = (m + q < N_) ? (short)f2b(acc[ti][q]) : (short)0;
        *(short4_t*)(Cb + (long)j*KPAD + m) = hv;
      }
    }
  }
}

// ---------------------------------------------------------------------------
// xesP[seg][b][e2] = sum_{e1 in seg} u[b,e1]*hodge[e1,e2]  (plain stores,
// no atomics; "+v" folded into k_redxes). grid (12 e2-chunks, SEGS=25).
// ---------------------------------------------------------------------------
__global__ void k_hodge(const float* __restrict__ u, const float* __restrict__ hodge,
                        float* __restrict__ xesP) {
  const int t = threadIdx.x;
  const int e2 = blockIdx.x*256 + t;
  const int seg = blockIdx.y;
  const int e1a = seg*ECH;
  __shared__ float ul[ECH*16];
  for (int idx = t; idx < ECH*16; idx += 256) {
    int bb = idx / ECH, ee = idx - bb*ECH;
    ul[ee*16 + bb] = u[bb*E_ + e1a + ee];
  }
  __syncthreads();
  if (e2 >= E_) return;
  float acc[16] = {};
  for (int ee = 0; ee < ECH; ee += 8) {
    float h[8];
#pragma unroll
    for (int q = 0; q < 8; ++q) h[q] = hodge[(long)(e1a + ee + q)*E_ + e2];
#pragma unroll
    for (int q = 0; q < 8; ++q) {
#pragma unroll
      for (int g4 = 0; g4 < 4; ++g4) {
        f32x4 u4 = *(const f32x4*)&ul[(ee + q)*16 + g4*4];
        acc[g4*4+0] += u4.x*h[q];
        acc[g4*4+1] += u4.y*h[q];
        acc[g4*4+2] += u4.z*h[q];
        acc[g4*4+3] += u4.w*h[q];
      }
    }
  }
#pragma unroll
  for (int bb = 0; bb < 16; ++bb)
    xesP[((long)seg*16 + bb)*E_ + e2] = acc[bb];
}

// xes[b,e] = sum_seg xesP[seg][b][e] + v[b,e]
__global__ void k_redxes(const float* __restrict__ xesP, const float* __restrict__ v,
                         float* __restrict__ xes) {
  int idx = blockIdx.x*256 + threadIdx.x;
  if (idx >= B_*E_) return;
  int b = idx / E_, e = idx - b*E_;
  float s = v[idx];
#pragma unroll
  for (int q = 0; q < SEGS; ++q) s += xesP[((long)q*16 + b)*E_ + e];
  xes[idx] = s;
}

// ---------------------------------------------------------------------------
// k_inc v3: xenP[cy][b][n] = (1/3)*sum_{e in chunk cy} xes[b,e]*inc[n,e]
// grid (250 n-tiles of 8, 4 e-chunks of 768). xes chunk staged in LDS;
// waves own 2 n-rows; coalesced f32x4 inc reads; butterfly reduce.
// ---------------------------------------------------------------------------
__global__ __launch_bounds__(256) void k_inc(const float* __restrict__ xes,
                                             const float* __restrict__ inc,
                                             float* __restrict__ xenP) {
  __shared__ float xes_l[16*EPAD];  // 48 KB
  const int t = threadIdx.x;
  const int wv = t >> 6, lane = t & 63;
  const int cy = blockIdx.y;
  const int n0 = blockIdx.x*8;
  // stage xes[:, cy*768 .. +768) -> LDS, zero pad past E_
  for (int i4 = t; i4 < 16*(EPAD/4); i4 += 256) {   // 12 iters
    int row = i4 / (EPAD/4);
    int el = (i4 - row*(EPAD/4)) << 2;
    int e = cy*EPAD + el;
    f32x4 vv = {0.f,0.f,0.f,0.f};
    if (e < E_) vv = *(const f32x4*)(xes + (long)row*E_ + e);
    *(f32x4*)&xes_l[row*EPAD + el] = vv;
  }
  __syncthreads();
  const int na = n0 + wv*2;
  const int nb = na + 1;
  const float* rowA = inc + (long)na*E_ + cy*EPAD;
  const float* rowB = inc + (long)nb*E_ + cy*EPAD;
  float accA[16] = {}, accB[16] = {};
#pragma unroll
  for (int g = 0; g < 3; ++g) {
    int e4 = (g*64 + lane) << 2;
    bool ok = (cy*EPAD + e4) < E_;
    f32x4 ia = {0.f,0.f,0.f,0.f}, ib = {0.f,0.f,0.f,0.f};
    if (ok) { ia = *(const f32x4*)(rowA + e4); ib = *(const f32x4*)(rowB + e4); }
#pragma unroll
    for (int b = 0; b < 16; ++b) {
      f32x4 xs = *(const f32x4*)&xes_l[b*EPAD + e4];
      accA[b] += xs.x*ia.x + xs.y*ia.y + xs.z*ia.z + xs.w*ia.w;
      accB[b] += xs.x*ib.x + xs.y*ib.y + xs.z*ib.z + xs.w*ib.w;
    }
  }
  // cross-lane reduce (all 64 lanes end with the sum)
#pragma unroll
  for (int b = 0; b < 16; ++b) {
#pragma unroll
    for (int off = 32; off > 0; off >>= 1) {
      accA[b] += __shfl_xor(accA[b], off, 64);
      accB[b] += __shfl_xor(accB[b], off, 64);
    }
  }
  // static-index extraction (no scratch), lanes 0-15 -> row na, 16-31 -> nb
  const int bl = lane & 15;
  float oA = 0.f, oB = 0.f;
#pragma unroll
  for (int b = 0; b < 16; ++b)
    if (bl == b) { oA = accA[b]; oB = accB[b]; }
  if (lane < 16)
    xenP[((long)cy*16 + bl)*N_ + na] = oA*(1.f/3.f);
  else if (lane < 32)
    xenP[((long)cy*16 + bl)*N_ + nb] = oB*(1.f/3.f);
}

// ---------------------------------------------------------------------------
// k_tail1: diffusion epilogue (o<64): 4 nodes/block, ne in regs, xs from
// C32a/C32b f32 (L2), W in LDS bf16 (bias = ki 51 row). 500 blocks.
// ---------------------------------------------------------------------------
#define NPC 4
__global__ __launch_bounds__(256) void k_tail1(const float* __restrict__ x,
                          const float* __restrict__ C32a,
                          const float* __restrict__ C32b,
                          const float* __restrict__ ne,
                          const float* __restrict__ wp,
                          const float* __restrict__ bp,
                          float* __restrict__ out) {
  __shared__ ushort_t W_l[NPC*52*64];
  __shared__ float xs_l[NPC*52*20];
  const int t = threadIdx.x;
  const int n0 = blockIdx.x*NPC;
  const int lane = t & 63, wv = t >> 6;
  float nev[NPC][16];
#pragma unroll
  for (int p = 0; p < NPC; ++p)
#pragma unroll
    for (int q = 0; q < 4; ++q)
      *(f32x4*)&nev[p][q*4] = *(const f32x4*)(ne + (n0 + p)*D_ + q*4);
  for (int idx = t; idx < 52*64; idx += 256) {
    int ki = idx >> 6, o = idx & 63;
    float a[NPC] = {};
#pragma unroll
    for (int d = 0; d < 16; ++d) {
      float w = (ki < KI_) ? wp[d*3264 + idx] : bp[d*256 + o];
#pragma unroll
      for (int p = 0; p < NPC; ++p) a[p] += nev[p][d]*w;
    }
#pragma unroll
    for (int p = 0; p < NPC; ++p) W_l[p*3328 + idx] = f2b(a[p]);
  }
  for (int idx = t; idx < KI_*64; idx += 256) {
    int ki = idx >> 6;
    int b = (idx >> 2) & 15, p = idx & 3;
    int k = ki / C_, cc = ki - k*C_;
    int n = n0 + p;
    float v;
    if (k == 0)      v = x[(b*N_ + n)*C_ + cc];
    else if (k == 1) v = C32a[(long)(b*C_ + cc)*KPAD + n];
    else             v = C32b[(long)(b*C_ + cc)*KPAD + n];
    xs_l[p*1040 + ki*20 + b] = v;
  }
  if (t < 64) xs_l[(t & 3)*1040 + KI_*20 + (t >> 2)] = 1.0f;
  __syncthreads();
  const int o = lane, bg = wv;
#pragma unroll
  for (int p = 0; p < NPC; ++p) {
    f32x4 acc = {0.f,0.f,0.f,0.f};
    for (int ki = 0; ki < 52; ++ki) {
      float w = b2f_u(W_l[p*3328 + ki*64 + o]);
      f32x4 xs4 = *(const f32x4*)&xs_l[p*1040 + ki*20 + bg*4];
      acc += xs4 * w;
    }
#pragma unroll
    for (int j = 0; j < 4; ++j)
      out[((long)((bg*4 + j)*N_ + n0 + p))*O_ + o] = acc[j];
  }
}

// ---------------------------------------------------------------------------
// k_tail2: o in [64,256) streaming writer. 2 nodes/block (1000 blocks).
// Phase A: per-(node,o) weights/bias + ZFC gather + per-(b,n) scalars in LDS
// (~7 KB). Phase B: flat coalesced write loop (24 iters, 192-float runs).
// o' = o-64: [0,32)=ZFC, [32,160)=temporal (wwt), [160,192)=supra (wws).
// (r3 bug fixed: zf_l[384..511] was never staged -> garbage for b>=12.)
// ---------------------------------------------------------------------------
#define NT2 2
__global__ __launch_bounds__(256) void k_tail2(const float* __restrict__ ne,
                          const float* __restrict__ bp,
                          const float* __restrict__ wwt, const float* __restrict__ wws,
                          const float* __restrict__ zfc, const float* __restrict__ gnnb,
                          const float* __restrict__ g, const float* __restrict__ xw,
                          const float* __restrict__ xenP,
                          float* __restrict__ out) {
  __shared__ float ne_l[NT2][16];
  __shared__ float wb[NT2][160];     // weight for o' in [32,192)
  __shared__ float bi[NT2][192];     // bias for o' in [0,192)
  __shared__ float gi_l[NT2][32], gb_l[NT2][32];
  __shared__ int   q_l[NT2][32];
  __shared__ float zf_l[16*32];
  __shared__ float xwv[16][NT2], xev[16][NT2];
  const int t = threadIdx.x;
  const int n0 = blockIdx.x*NT2;
  // phase 0: independent staging (512 zfc floats: 2 per thread)
  zf_l[t] = zfc[t];
  zf_l[t + 256] = zfc[t + 256];
  if (t < NT2*16) ne_l[t >> 4][t & 15] = ne[(n0 + (t >> 4))*16 + (t & 15)];
  if (t < NT2*32) {
    int nl = t >> 5, j = t & 31;
    int flat = (n0 + nl)*32 + j;
    int q = flat / N_;
    int i = flat - q*N_;
    q_l[nl][j] = q;
    gi_l[nl][j] = g[i];
    gb_l[nl][j] = gnnb[i];
  }
  if (t < 16*NT2) {
    int b = t / NT2, nl = t - b*NT2;
    int n = n0 + nl;
    xwv[b][nl] = xw[b*N_ + n];
    xev[b][nl] = xenP[b*N_ + n] + xenP[(16 + b)*N_ + n]
               + xenP[(32 + b)*N_ + n] + xenP[(48 + b)*N_ + n];
  }
  __syncthreads();
  // phase 1: weights + bias (uses ne_l)
  for (int idx = t; idx < NT2*192; idx += 256) {
    int nl = idx / 192, op = idx - nl*192;
    float wv = 0.f, bv = 0.f;
#pragma unroll
    for (int d = 0; d < 16; ++d) {
      float nd = ne_l[nl][d];
      bv += nd * bp[d*256 + 64 + op];
      float ww = 0.f;
      if (op >= 32 && op < 160) ww = wwt[d*128 + (op - 32)];
      else if (op >= 160)       ww = wws[d*32 + (op - 160)];
      wv += nd * ww;
    }
    bi[nl][op] = bv;
    if (op >= 32) wb[nl][op - 32] = wv;
  }
  __syncthreads();
  // phase 2: flat write loop, 16*NT2*192 = 6144 elements, 24 iters
  for (int idx = t; idx < 16*NT2*192; idx += 256) {
    int b = idx / (NT2*192);
    int r = idx - b*(NT2*192);
    int nl = r / 192, op = r - nl*192;
    float val;
    if (op < 32) {
      float z = zf_l[b*32 + q_l[nl][op]]*gi_l[nl][op] + gb_l[nl][op];
      val = z > 0.f ? z : 0.f;
    } else if (op < 160) {
      val = xwv[b][nl] * wb[nl][op - 32];
    } else {
      val = xev[b][nl] * wb[nl][op - 32];
    }
    out[((long)(b*N_ + n0 + nl))*O_ + 64 + op] = val + bi[nl][op];
  }
}

extern "C" void kernel_launch(void* const* d_in, const int* in_sizes, int n_in,
                              void* d_out, int out_size, void* d_ws, size_t ws_size,
                              hipStream_t stream) {
  const float* x     = (const float*)d_in[0];
  const float* xwin  = (const float*)d_in[1];
  const float* ne    = (const float*)d_in[2];
  // d_in[3] fixed_adj == 0 -> softmax branch (adj d_in[4] unused)
  const int*   stay  = (const int*)d_in[5];
  const int*   jc    = (const int*)d_in[6];
  const float* zfc   = (const float*)d_in[7];
  const float* hodge = (const float*)d_in[8];
  const float* xew   = (const float*)d_in[9];
  const float* inc   = (const float*)d_in[10];
  const float* wp    = (const float*)d_in[11];
  const float* wws   = (const float*)d_in[12];
  const float* wwt   = (const float*)d_in[13];
  const float* bp    = (const float*)d_in[14];
  const float* Tp    = (const float*)d_in[15];
  const float* lw    = (const float*)d_in[16];
  const float* lb    = (const float*)d_in[17];
  const float* gw    = (const float*)d_in[18];
  const float* gnnb  = (const float*)d_in[19];
  const int*   bidx  = (const int*)d_in[20];
  float* out = (float*)d_out;

  // d_ws: only what k_tail* (the out-writers) read, plus small intermediates.
  char* wsb = (char*)d_ws;
  float*    C32a = (float*)(wsb);                 // 288*2048*4 = 2,359,296
  float*    C32b = (float*)(wsb + 2359296);       // 2,359,296
  // BT1 aliases the first half of C32b: BT1 dead after k_mm2 #1; C32b is
  // written by k_mm2 #2, which runs after. Stream-ordered, safe.
  ushort_t* BT1  = (ushort_t*)(wsb + 2359296);    // 1,179,648
  float* u    = (float*)(wsb + 4718592);          // 192,000
  float* v    = (float*)(wsb + 4910592);          // 192,000
  float* xes  = (float*)(wsb + 5102592);          // 192,000
  float* xw   = (float*)(wsb + 5294592);          // 128,000
  float* g    = (float*)(wsb + 5422592);          //   8,000
  float* xenP = (float*)(wsb + 5430592);          // 512,000 -> total 5,942,592 B

  // d_out as scratch for buffers dead before k_tail1/2 (they write every
  // output element, and read none of these):
  char* ob = (char*)d_out;
  ushort_t* S    = (ushort_t*)(ob);               // [2048][2048] bf16 = 8,388,608
  ushort_t* BT2  = (ushort_t*)(ob + 8388608);     // 1,179,648
  float*    xesP = (float*)(ob + 9568256);        // SEGS*16*E_*4 = 4,800,000 -> 14,368,256 (< 32.7 MB)

  k_small<<<2601, 256, 0, stream>>>(xew, bidx, lw, lb, jc, u, v,
                                    xwin, Tp, xw, gw, g, x, BT1);
  k_S<<<2048, 256, 0, stream>>>(ne, stay, S);
  k_mm2<<<dim3(128,2), 256, 0, stream>>>(S, BT1, C32a, BT2, 1);      // xs1^T (f32 + bf16)
  k_mm2<<<dim3(128,2), 256, 0, stream>>>(S, BT2, C32b, nullptr, 0);  // xs2^T (f32)
  k_hodge<<<dim3(12, SEGS), 256, 0, stream>>>(u, hodge, xesP);
  k_redxes<<<188, 256, 0, stream>>>(xesP, v, xes);
  k_inc<<<dim3(250, 4), 256, 0, stream>>>(xes, inc, xenP);
  k_tail1<<<500, 256, 0, stream>>>(x, C32a, C32b, ne, wp, bp, out);
  k_tail2<<<1000, 256, 0, stream>>>(ne, bp, wwt, wws, zfc, gnnb, g, xw,
                                    xenP, out);
}